// Round 12
// baseline (166.951 us; speedup 1.0000x reference)
//
#include <hip/hip_runtime.h>
#include <cmath>

#define NN 8192
#define DD 512
#define NSRC 8
#define PSW 8                  // ps partials per row = 8 column groups
#define COFF 100.0f            // fixed softmax offset

typedef __bf16 bf16x8 __attribute__((ext_vector_type(8)));
typedef float  f32x4  __attribute__((ext_vector_type(4)));

__device__ __forceinline__ unsigned short f2bf(float f) {
    unsigned u = __float_as_uint(f);
    u += 0x7fffu + ((u >> 16) & 1u);
    return (unsigned short)(u >> 16);
}

// ---------------------------------------------------------------------------
// Kernel A (kept): blocks 0..127 per-source text sums; blocks 128..:
// wave-per-row cast of img+txt AND per-row img.txt dot (ds) for free.
// ---------------------------------------------------------------------------
__global__ __launch_bounds__(256) void k_prep(
    const float* __restrict__ img, const float* __restrict__ txt,
    const int* __restrict__ labels,
    unsigned short* __restrict__ imgB, unsigned short* __restrict__ txtB,
    float* __restrict__ Tsum, int* __restrict__ counts,
    float* __restrict__ dsv)
{
    const int tid = threadIdx.x;
    if (blockIdx.x >= 128) {
        const int wv   = tid >> 6;
        const int lane = tid & 63;
        const int row  = (blockIdx.x - 128) * 4 + wv;
        const size_t base = (size_t)row * DD + lane * 8;
        const float4 i0 = *(const float4*)(img + base);
        const float4 i1 = *(const float4*)(img + base + 4);
        const float4 t0 = *(const float4*)(txt + base);
        const float4 t1 = *(const float4*)(txt + base + 4);
        union { unsigned short s[8]; uint4 v; } oi, ot;
        oi.s[0] = f2bf(i0.x); oi.s[1] = f2bf(i0.y); oi.s[2] = f2bf(i0.z); oi.s[3] = f2bf(i0.w);
        oi.s[4] = f2bf(i1.x); oi.s[5] = f2bf(i1.y); oi.s[6] = f2bf(i1.z); oi.s[7] = f2bf(i1.w);
        ot.s[0] = f2bf(t0.x); ot.s[1] = f2bf(t0.y); ot.s[2] = f2bf(t0.z); ot.s[3] = f2bf(t0.w);
        ot.s[4] = f2bf(t1.x); ot.s[5] = f2bf(t1.y); ot.s[6] = f2bf(t1.z); ot.s[7] = f2bf(t1.w);
        *(uint4*)(imgB + base) = oi.v;
        *(uint4*)(txtB + base) = ot.v;
        float ds = i0.x * t0.x + i0.y * t0.y + i0.z * t0.z + i0.w * t0.w
                 + i1.x * t1.x + i1.y * t1.y + i1.z * t1.z + i1.w * t1.w;
#pragma unroll
        for (int off = 32; off; off >>= 1) ds += __shfl_xor(ds, off);
        if (lane == 0) dsv[row] = ds;
        return;
    }
    __shared__ float Tacc[NSRC * DD];
    __shared__ int cacc[NSRC];
    const int d0 = 2 * tid;
#pragma unroll
    for (int s = 0; s < NSRC; s++) {
        Tacc[s * DD + d0] = 0.f;
        Tacc[s * DD + d0 + 1] = 0.f;
    }
    if (tid < NSRC) cacc[tid] = 0;
    __syncthreads();

    const int row0 = blockIdx.x * 64;
    if (tid < 64) atomicAdd(&cacc[labels[row0 + tid]], 1);

    for (int j = 0; j < 64; j++) {
        const int lab = labels[row0 + j];
        const float2 v = *(const float2*)(txt + (size_t)(row0 + j) * DD + d0);
        Tacc[lab * DD + d0]     += v.x;
        Tacc[lab * DD + d0 + 1] += v.y;
    }
    __syncthreads();
#pragma unroll
    for (int k = 0; k < NSRC * DD / 256; k++) {
        const int e = k * 256 + tid;
        atomicAdd(&Tsum[e], Tacc[e]);
    }
    if (tid < NSRC) atomicAdd(&counts[tid], cacc[tid]);
}

// ---------------------------------------------------------------------------
// Kernel B (R12): 128x128 tile / 64 KiB LDS -> 2 INDEPENDENT blocks per CU.
// Mechanism: intra-block overlap is barrier-blocked (R5/R7/R8/R11 all null);
// independent co-resident blocks interleave freely on the CU (m114), so one
// block's MFMA clusters hide the other's LDS drains/barrier waits.
// Phase machine = R11's proven minimal-barrier template scaled down:
//   4 waves 2wr x 2wc, per-wave 64x64 out (acc[4][4], 64 VGPR);
//   2 phases/tile (JH0: af8+bf4 reads, 16 MFMA; JH1: bf4 reads, 16 MFMA);
//   2 barriers/tile (bar_M after JH0's MFMA; bar_S after vmcnt(2));
//   staging quanta 32 rows x 64 K = 4 KB (256 thr x 16B);
//   schedule: JH0 stages 6 (A(t+1)q2q3 + B(t+1)q0-3), JH1 stages 2
//   (A(t+2)q0q1) + vmcnt(2). Outstanding 2+6+2=10 -> wait retires exactly
//   tile t+1 (re-derived). WAR: STG2 overwrites A q0q1 whose readers (wr0 af,
//   JH0) retired at bar_M; STG1 targets NXT buf, last read before prev bar_S.
// Read pattern: identical 16-row/ln/lq/xsw class as R9/R11 (0 conflicts).
// Persistent: 64 virtual tiles (8 ct x 8 kt), exp flush at ct boundaries.
// XCD map keeps all 8 same-A-panel blocks on one XCD.
// ---------------------------------------------------------------------------
__global__ __launch_bounds__(256, 2) void k_lse_mfma128(
    const unsigned short* __restrict__ imgB, const unsigned short* __restrict__ txtB,
    const float* __restrict__ scale_p, float* __restrict__ ps)
{
    __shared__ uint4 lds[4096];            // 64 KiB: 2 buf x (A 16K | B 16K)
    const float scale = scale_p[0];
    const int tid  = threadIdx.x;
    const int lane = tid & 63;
    const int w    = tid >> 6;             // wave 0..3
    const int wr   = w >> 1;               // 0..1: 64-row half
    const int wc   = w & 1;                // 0..1: 64-col half
    const int lq   = lane >> 4;
    const int ln   = lane & 15;
    const int c    = blockIdx.x & 7;       // XCD (round-robin dispatch)
    const int l    = blockIdx.x >> 3;      // 0..63
    const int by   = c * 8 + (l >> 3);     // row panel 0..63
    const int bcg  = l & 7;                // column group 0..7 (1024 cols)
    const int row0    = by * 128;
    const int colBase = bcg * 1024;

    const int st_r  = tid >> 3;            // 0..31 rows per quantum
    const int st_kc = (tid & 7) ^ (st_r & 7);
    const int xsw   = ln & 7;

    // precomputed ds_read byte bases [buf][ks]; ii/jh/jj deltas compile-time.
    int aA[2][2], aB[2][2];
#pragma unroll
    for (int b = 0; b < 2; b++)
#pragma unroll
        for (int ks = 0; ks < 2; ks++) {
            const int perm = ((ks << 2) + lq) ^ xsw;
            aA[b][ks] = b * 32768 + (wr * 64 + ln) * 128 + perm * 16;
            aB[b][ks] = b * 32768 + 16384 + (wc * 64 + ln) * 128 + perm * 16;
        }
    const unsigned short* gA0 = imgB + (size_t)(row0 + st_r) * DD + (st_kc << 3);
    const unsigned short* gB0 = txtB + (size_t)(colBase + st_r) * DD + (st_kc << 3);

#define SA(BUF, Q, T)                                                          \
    { const unsigned short* g = gA0 + ((Q) << 14) + (((T) & 7) << 6);          \
      __builtin_amdgcn_global_load_lds(                                        \
          (const __attribute__((address_space(1))) void*)g,                    \
          (__attribute__((address_space(3))) void*)                            \
              &lds[(BUF) * 2048 + (Q) * 256 + tid], 16, 0, 0); }
#define SB(BUF, Q, T)                                                          \
    { const unsigned short* g = gB0 + ((size_t)(((T) >> 3) & 7) << 16)         \
          + ((Q) << 14) + (((T) & 7) << 6);                                    \
      __builtin_amdgcn_global_load_lds(                                        \
          (const __attribute__((address_space(1))) void*)g,                    \
          (__attribute__((address_space(3))) void*)                            \
              &lds[(BUF) * 2048 + 1024 + (Q) * 256 + tid], 16, 0, 0); }

// Phase JH of the tile in BUF: reads -> STG -> sched_barrier ->
// setprio(1) 16 MFMA setprio(0). RA=1 only at JH0 (af held across tile).
#define PH_(BUF, JH, RA, STG)                                                  \
    do {                                                                       \
        if (RA) {                                                              \
            _Pragma("unroll") for (int ks = 0; ks < 2; ks++)                   \
                _Pragma("unroll") for (int ii = 0; ii < 4; ii++)               \
                    af[ii][ks] = *reinterpret_cast<const bf16x8*>(             \
                        (const char*)lds + aA[BUF][ks] + ii * 2048);           \
        }                                                                      \
        bf16x8 bf[2][2];                                                       \
        _Pragma("unroll") for (int ks = 0; ks < 2; ks++)                       \
            _Pragma("unroll") for (int jj = 0; jj < 2; jj++)                   \
                bf[jj][ks] = *reinterpret_cast<const bf16x8*>(                 \
                    (const char*)lds + aB[BUF][ks] + (JH) * 4096 + jj * 2048); \
        STG;                                                                   \
        __builtin_amdgcn_sched_barrier(0);                                     \
        __builtin_amdgcn_s_setprio(1);                                         \
        _Pragma("unroll") for (int ks = 0; ks < 2; ks++) {                     \
            _Pragma("unroll") for (int ii = 0; ii < 4; ii++) {                 \
                _Pragma("unroll") for (int jj = 0; jj < 2; jj++) {             \
                    acc[ii][(JH) * 2 + jj] =                                   \
                        __builtin_amdgcn_mfma_f32_16x16x32_bf16(               \
                            af[ii][ks], bf[jj][ks], acc[ii][(JH) * 2 + jj],    \
                            0, 0, 0);                                          \
                }                                                              \
            }                                                                  \
        }                                                                      \
        __builtin_amdgcn_s_setprio(0);                                         \
    } while (0)

    // ---- prologue: tile 0 fully + tile 1 Aq0,Aq1 ----
#pragma unroll
    for (int q = 0; q < 4; q++) SA(0, q, 0);
#pragma unroll
    for (int q = 0; q < 4; q++) SB(0, q, 0);
    SA(1, 0, 1); SA(1, 1, 1);
    asm volatile("s_waitcnt vmcnt(2)" ::: "memory");   // tile 0 landed
    __builtin_amdgcn_s_barrier();

    f32x4 acc[4][4];
    f32x4 s_run[4];
#pragma unroll
    for (int i = 0; i < 4; i++) {
        s_run[i] = (f32x4){0.f, 0.f, 0.f, 0.f};
#pragma unroll
        for (int j = 0; j < 4; j++) acc[i][j] = (f32x4){0.f, 0.f, 0.f, 0.f};
    }
    bf16x8 af[4][2];

#pragma unroll 1
    for (int v0 = 0; v0 < 64; v0 += 2) {
        // ---- tile t (buf0) ----
        PH_(0, 0, 1,
            SA(1, 2, v0 + 1); SA(1, 3, v0 + 1);
            SB(1, 0, v0 + 1); SB(1, 1, v0 + 1);
            SB(1, 2, v0 + 1); SB(1, 3, v0 + 1));
        __builtin_amdgcn_s_barrier();      // bar_M: af(buf0) reads retired
        PH_(0, 1, 0, SA(0, 0, v0 + 2); SA(0, 1, v0 + 2));
        asm volatile("s_waitcnt vmcnt(2)" ::: "memory");
        __builtin_amdgcn_s_barrier();      // bar_S: t+1 landed, buf0 retired
        // ---- tile t+1 (buf1) ----
        PH_(1, 0, 1,
            SA(0, 2, v0 + 2); SA(0, 3, v0 + 2);
            SB(0, 0, v0 + 2); SB(0, 1, v0 + 2);
            SB(0, 2, v0 + 2); SB(0, 3, v0 + 2));
        __builtin_amdgcn_s_barrier();      // bar_M'
        PH_(1, 1, 0, SA(1, 0, v0 + 3); SA(1, 1, v0 + 3));
        asm volatile("s_waitcnt vmcnt(2)" ::: "memory");
        __builtin_amdgcn_s_barrier();      // bar_S'
        if ((v0 & 6) == 6) {
            // ct boundary: register-only exp flush (no barrier, no loads)
#pragma unroll
            for (int i = 0; i < 4; i++) {
#pragma unroll
                for (int rg = 0; rg < 4; rg++) {
                    float es = s_run[i][rg];
#pragma unroll
                    for (int j = 0; j < 4; j++)
                        es += __expf(fmaf(acc[i][j][rg], scale, -COFF));
                    s_run[i][rg] = es;
                }
#pragma unroll
                for (int j = 0; j < 4; j++)
                    acc[i][j] = (f32x4){0.f, 0.f, 0.f, 0.f};
            }
        }
    }

    asm volatile("s_waitcnt vmcnt(0)" ::: "memory");
    __syncthreads();

    // ---- epilogue: reduce s_run across ln, fold 2 wc-waves via LDS ----
    float* fred = (float*)lds;             // 128 rows x 2 wc floats
#pragma unroll
    for (int i = 0; i < 4; i++) {
#pragma unroll
        for (int rg = 0; rg < 4; rg++) {
            float es = s_run[i][rg];
#pragma unroll
            for (int off = 8; off; off >>= 1) es += __shfl_xor(es, off);
            if (ln == 0)
                fred[(wr * 64 + i * 16 + lq * 4 + rg) * 2 + wc] = es;
        }
    }
    __syncthreads();
    if (tid < 128) {
        const float tot = fred[tid * 2] + fred[tid * 2 + 1];
        ps[(size_t)(row0 + tid) * PSW + bcg] = tot;
    }
#undef SA
#undef SB
#undef PH_
}

// ---------------------------------------------------------------------------
// Kernel C (kept): dt via bf16 imgB . fp32 Tsum; ds precomputed.
// ---------------------------------------------------------------------------
__global__ __launch_bounds__(256) void k_finalize(
    const unsigned short* __restrict__ imgB,
    const int* __restrict__ labels, const float* __restrict__ scale_p,
    const float* __restrict__ Tsum, const int* __restrict__ counts,
    const float* __restrict__ ps, const float* __restrict__ dsv,
    float* __restrict__ out)
{
    const float scale = scale_p[0];
    const int tid = threadIdx.x;
    const int lane = tid & 63;
    const int wave = tid >> 6;
    const int rowBase = blockIdx.x * 16 + wave * 4;
    float local = 0.f;
#pragma unroll
    for (int it = 0; it < 4; it++) {
        const int i = rowBase + it;
        const int lab = labels[i];
        const float* sp = Tsum + lab * DD + lane * 8;
        union { uint4 v; unsigned short s[8]; } iv;
        iv.v = *(const uint4*)(imgB + (size_t)i * DD + lane * 8);
        const float4 s0 = *(const float4*)(sp);
        const float4 s1 = *(const float4*)(sp + 4);
        float dt = 0.f;
        dt = fmaf(__uint_as_float((unsigned)iv.s[0] << 16), s0.x, dt);
        dt = fmaf(__uint_as_float((unsigned)iv.s[1] << 16), s0.y, dt);
        dt = fmaf(__uint_as_float((unsigned)iv.s[2] << 16), s0.z, dt);
        dt = fmaf(__uint_as_float((unsigned)iv.s[3] << 16), s0.w, dt);
        dt = fmaf(__uint_as_float((unsigned)iv.s[4] << 16), s1.x, dt);
        dt = fmaf(__uint_as_float((unsigned)iv.s[5] << 16), s1.y, dt);
        dt = fmaf(__uint_as_float((unsigned)iv.s[6] << 16), s1.z, dt);
        dt = fmaf(__uint_as_float((unsigned)iv.s[7] << 16), s1.w, dt);
        float es = (lane < PSW) ? ps[(size_t)i * PSW + lane] : 0.f;
#pragma unroll
        for (int off = 32; off; off >>= 1) {
            dt += __shfl_xor(dt, off);
            es += __shfl_xor(es, off);
        }
        if (lane == 0) {
            const float lse = COFF + __logf(es);
            const int cnt = counts[lab] - 1;
            if (cnt > 0) {
                const float row_sum = scale * (dt - dsv[i]) - (float)cnt * lse;
                local += row_sum / (float)cnt;
            }
        }
    }
    __shared__ float red[4];
    if (lane == 0) red[wave] = local;
    __syncthreads();
    if (tid == 0) {
        const float t = red[0] + red[1] + red[2] + red[3];
        atomicAdd(out, -t / (float)NN);
    }
}

// ---------------------------------------------------------------------------
extern "C" void kernel_launch(void* const* d_in, const int* in_sizes, int n_in,
                              void* d_out, int out_size, void* d_ws, size_t ws_size,
                              hipStream_t stream)
{
    const float* img     = (const float*)d_in[0];
    const float* txt     = (const float*)d_in[1];
    const float* scale_p = (const float*)d_in[2];
    const int*   labels  = (const int*)d_in[3];
    float* out = (float*)d_out;

    char* ws = (char*)d_ws;
    float* ps    = (float*)(ws);                                  // 256 KB (8192 x 8)
    float* Tsum  = (float*)(ws + (1 << 18));                      // 16 KB
    int*   counts = (int*)(ws + (1 << 18) + NSRC * DD * 4);
    float* dsv   = (float*)(ws + 0x48000);                        // 32 KB
    unsigned short* imgB = (unsigned short*)(ws + 2 * 1024 * 1024);   // 8 MB
    unsigned short* txtB = (unsigned short*)(ws + 10 * 1024 * 1024);  // 8 MB

    hipMemsetAsync(ws + (1 << 18), 0, NSRC * DD * 4 + 64, stream);  // Tsum+counts
    hipMemsetAsync(d_out, 0, 4, stream);                            // out

    k_prep<<<128 + NN / 4, 256, 0, stream>>>(
        img, txt, labels, imgB, txtB, Tsum, counts, dsv);
    k_lse_mfma128<<<512, 256, 0, stream>>>(imgB, txtB, scale_p, ps);
    k_finalize<<<NN / 16, 256, 0, stream>>>(imgB, labels, scale_p,
                                            Tsum, counts, ps, dsv, out);
}

// Round 13
// 157.754 us; speedup vs baseline: 1.0583x; 1.0583x over previous
//
#include <hip/hip_runtime.h>
#include <cmath>

#define NN 8192
#define DD 512
#define NSRC 8
#define PSW 8                  // ps partials per row = 8 column groups
#define COFF 100.0f            // fixed softmax offset

typedef __bf16 bf16x8 __attribute__((ext_vector_type(8)));
typedef float  f32x4  __attribute__((ext_vector_type(4)));

__device__ __forceinline__ unsigned short f2bf(float f) {
    unsigned u = __float_as_uint(f);
    u += 0x7fffu + ((u >> 16) & 1u);
    return (unsigned short)(u >> 16);
}

// ---------------------------------------------------------------------------
// Kernel A (R13): blocks 0..127 per-source text sums; blocks 128..: wave-per-
// row cast of img+txt AND per-row img.txt dot (ds). Block 128 additionally
// zeroes out[0] (stream-ordered before k_finalize's atomics) -> the separate
// d_out memset node is dropped (5 -> 4 graph nodes).
// ---------------------------------------------------------------------------
__global__ __launch_bounds__(256) void k_prep(
    const float* __restrict__ img, const float* __restrict__ txt,
    const int* __restrict__ labels,
    unsigned short* __restrict__ imgB, unsigned short* __restrict__ txtB,
    float* __restrict__ Tsum, int* __restrict__ counts,
    float* __restrict__ dsv, float* __restrict__ out)
{
    const int tid = threadIdx.x;
    if (blockIdx.x >= 128) {
        if (blockIdx.x == 128 && tid == 0) out[0] = 0.f;
        const int wv   = tid >> 6;
        const int lane = tid & 63;
        const int row  = (blockIdx.x - 128) * 4 + wv;
        const size_t base = (size_t)row * DD + lane * 8;
        const float4 i0 = *(const float4*)(img + base);
        const float4 i1 = *(const float4*)(img + base + 4);
        const float4 t0 = *(const float4*)(txt + base);
        const float4 t1 = *(const float4*)(txt + base + 4);
        union { unsigned short s[8]; uint4 v; } oi, ot;
        oi.s[0] = f2bf(i0.x); oi.s[1] = f2bf(i0.y); oi.s[2] = f2bf(i0.z); oi.s[3] = f2bf(i0.w);
        oi.s[4] = f2bf(i1.x); oi.s[5] = f2bf(i1.y); oi.s[6] = f2bf(i1.z); oi.s[7] = f2bf(i1.w);
        ot.s[0] = f2bf(t0.x); ot.s[1] = f2bf(t0.y); ot.s[2] = f2bf(t0.z); ot.s[3] = f2bf(t0.w);
        ot.s[4] = f2bf(t1.x); ot.s[5] = f2bf(t1.y); ot.s[6] = f2bf(t1.z); ot.s[7] = f2bf(t1.w);
        *(uint4*)(imgB + base) = oi.v;
        *(uint4*)(txtB + base) = ot.v;
        float ds = i0.x * t0.x + i0.y * t0.y + i0.z * t0.z + i0.w * t0.w
                 + i1.x * t1.x + i1.y * t1.y + i1.z * t1.z + i1.w * t1.w;
#pragma unroll
        for (int off = 32; off; off >>= 1) ds += __shfl_xor(ds, off);
        if (lane == 0) dsv[row] = ds;
        return;
    }
    __shared__ float Tacc[NSRC * DD];
    __shared__ int cacc[NSRC];
    const int d0 = 2 * tid;
#pragma unroll
    for (int s = 0; s < NSRC; s++) {
        Tacc[s * DD + d0] = 0.f;
        Tacc[s * DD + d0 + 1] = 0.f;
    }
    if (tid < NSRC) cacc[tid] = 0;
    __syncthreads();

    const int row0 = blockIdx.x * 64;
    if (tid < 64) atomicAdd(&cacc[labels[row0 + tid]], 1);

    for (int j = 0; j < 64; j++) {
        const int lab = labels[row0 + j];
        const float2 v = *(const float2*)(txt + (size_t)(row0 + j) * DD + d0);
        Tacc[lab * DD + d0]     += v.x;
        Tacc[lab * DD + d0 + 1] += v.y;
    }
    __syncthreads();
#pragma unroll
    for (int k = 0; k < NSRC * DD / 256; k++) {
        const int e = k * 256 + tid;
        atomicAdd(&Tsum[e], Tacc[e]);
    }
    if (tid < NSRC) atomicAdd(&counts[tid], cacc[tid]);
}

// ---------------------------------------------------------------------------
// Kernel B (R13): R11's winner reduced to the provable sync minimum:
// ONE barrier + ONE vmcnt(0) per K-tile.
// Schedule: tile T (buf B) stages ALL 8 quanta of tile T+1 into buf B^1 at
// JH0. No same-buffer overwrite exists anywhere: buf^1's last readers
// retired at the previous bar_S, which precedes the STG issue block-wide ->
// bar_M is dead, removed. vmcnt(0) at tile end drains exactly the 8 loads
// issued ~2000 cyc earlier (covers ~1170 cyc L2 service + latency).
// Fragment geometry / 0-conflict read pattern / registers / flush / epilogue
// identical to R11. Spill tripwire: WRITE_SIZE must stay 256 B.
// ---------------------------------------------------------------------------
__global__ __launch_bounds__(512, 2) void k_lse_mfma256(
    const unsigned short* __restrict__ imgB, const unsigned short* __restrict__ txtB,
    const float* __restrict__ scale_p, float* __restrict__ ps)
{
    __shared__ uint4 lds[8192];            // 128 KiB
    const float scale = scale_p[0];
    const int tid  = threadIdx.x;
    const int lane = tid & 63;
    const int w    = tid >> 6;
    const int wr   = w >> 1;               // 0..3: 64-row quarter
    const int wc   = w & 1;                // 0..1: 128-col half
    const int lq   = lane >> 4;
    const int ln   = lane & 15;
    const int c    = blockIdx.x & 7;       // XCD (round-robin dispatch)
    const int l    = blockIdx.x >> 3;
    const int by   = c * 4 + (l >> 3);     // row panel 0..31
    const int bcg  = l & 7;                // column group 0..7
    const int row0    = by * 256;
    const int colBase = bcg * 1024;

    const int st_r  = tid >> 3;
    const int st_kc = (tid & 7) ^ (st_r & 7);
    const int xsw   = ln & 7;

    int aA[2][2], aB[2][2];
#pragma unroll
    for (int b = 0; b < 2; b++)
#pragma unroll
        for (int ks = 0; ks < 2; ks++) {
            const int perm = ((ks << 2) + lq) ^ xsw;
            aA[b][ks] = b * 65536 + (wr * 64 + ln) * 128 + perm * 16;
            aB[b][ks] = b * 65536 + 32768 + (wc * 128 + ln) * 128 + perm * 16;
        }
    const unsigned short* gA0 = imgB + (size_t)(row0 + st_r) * DD + (st_kc << 3);
    const unsigned short* gB0 = txtB + (size_t)(colBase + st_r) * DD + (st_kc << 3);

#define SA(BUF, Q, T)                                                          \
    { const unsigned short* g = gA0 + ((Q) << 15) + (((T) & 7) << 6);          \
      __builtin_amdgcn_global_load_lds(                                        \
          (const __attribute__((address_space(1))) void*)g,                    \
          (__attribute__((address_space(3))) void*)                            \
              &lds[(BUF) * 4096 + (Q) * 512 + tid], 16, 0, 0); }
#define SB(BUF, Q, T)                                                          \
    { const unsigned short* g = gB0 + ((size_t)(((T) >> 3) & 3) << 17)         \
          + ((Q) << 15) + (((T) & 7) << 6);                                    \
      __builtin_amdgcn_global_load_lds(                                        \
          (const __attribute__((address_space(1))) void*)g,                    \
          (__attribute__((address_space(3))) void*)                            \
              &lds[(BUF) * 4096 + 2048 + (Q) * 512 + tid], 16, 0, 0); }

#define STG8(BUF, T)                                                           \
    SA(BUF, 0, T); SA(BUF, 1, T); SA(BUF, 2, T); SA(BUF, 3, T);                \
    SB(BUF, 0, T); SB(BUF, 1, T); SB(BUF, 2, T); SB(BUF, 3, T)

// Phase JH of the tile in BUF (no barrier inside): reads -> STG ->
// sched_barrier -> setprio(1) MFMA setprio(0). RA=1 only at JH0.
#define PH_(BUF, JH, RA, STG)                                                  \
    do {                                                                       \
        if (RA) {                                                              \
            _Pragma("unroll") for (int ks = 0; ks < 2; ks++)                   \
                _Pragma("unroll") for (int ii = 0; ii < 4; ii++)               \
                    af[ii][ks] = *reinterpret_cast<const bf16x8*>(             \
                        (const char*)lds + aA[BUF][ks] + ii * 2048);           \
        }                                                                      \
        bf16x8 bf[2][2];                                                       \
        _Pragma("unroll") for (int ks = 0; ks < 2; ks++)                       \
            _Pragma("unroll") for (int jj = 0; jj < 2; jj++)                   \
                bf[jj][ks] = *reinterpret_cast<const bf16x8*>(                 \
                    (const char*)lds + aB[BUF][ks] + (JH) * 4096 + jj * 2048); \
        STG;                                                                   \
        __builtin_amdgcn_sched_barrier(0);                                     \
        __builtin_amdgcn_s_setprio(1);                                         \
        _Pragma("unroll") for (int ks = 0; ks < 2; ks++) {                     \
            _Pragma("unroll") for (int ii = 0; ii < 4; ii++) {                 \
                _Pragma("unroll") for (int jj = 0; jj < 2; jj++) {             \
                    acc[ii][(JH) * 2 + jj] =                                   \
                        __builtin_amdgcn_mfma_f32_16x16x32_bf16(               \
                            af[ii][ks], bf[jj][ks], acc[ii][(JH) * 2 + jj],    \
                            0, 0, 0);                                          \
                }                                                              \
            }                                                                  \
        }                                                                      \
        __builtin_amdgcn_s_setprio(0);                                         \
    } while (0)

    // ---- prologue: stage tile 0 into buf0, drain, sync ----
    STG8(0, 0);
    asm volatile("s_waitcnt vmcnt(0)" ::: "memory");
    __builtin_amdgcn_s_barrier();

    f32x4 acc[4][8];
    f32x4 s_run[4];
#pragma unroll
    for (int i = 0; i < 4; i++) {
        s_run[i] = (f32x4){0.f, 0.f, 0.f, 0.f};
#pragma unroll
        for (int j = 0; j < 8; j++) acc[i][j] = (f32x4){0.f, 0.f, 0.f, 0.f};
    }
    bf16x8 af[4][2];

#pragma unroll 1
    for (int v0 = 0; v0 < 32; v0 += 2) {
        // ---- tile v0 (buf0): stage v0+1 -> buf1 at JH0 ----
        PH_(0, 0, 1, STG8(1, v0 + 1));
        PH_(0, 1, 0, (void)0);
        PH_(0, 2, 0, (void)0);
        PH_(0, 3, 0, (void)0);
        asm volatile("s_waitcnt vmcnt(0)" ::: "memory");
        __builtin_amdgcn_s_barrier();      // bar_S: v0+1 staged, buf0 retired
        // ---- tile v0+1 (buf1): stage v0+2 -> buf0 at JH0 ----
        PH_(1, 0, 1, STG8(0, v0 + 2));
        PH_(1, 1, 0, (void)0);
        PH_(1, 2, 0, (void)0);
        PH_(1, 3, 0, (void)0);
        asm volatile("s_waitcnt vmcnt(0)" ::: "memory");
        __builtin_amdgcn_s_barrier();      // bar_S'
        if ((v0 & 6) == 6) {
            // ct boundary: register-only exp flush (no barrier, no loads)
#pragma unroll
            for (int i = 0; i < 4; i++) {
#pragma unroll
                for (int rg = 0; rg < 4; rg++) {
                    float es = s_run[i][rg];
#pragma unroll
                    for (int j = 0; j < 8; j++)
                        es += __expf(fmaf(acc[i][j][rg], scale, -COFF));
                    s_run[i][rg] = es;
                }
#pragma unroll
                for (int j = 0; j < 8; j++)
                    acc[i][j] = (f32x4){0.f, 0.f, 0.f, 0.f};
            }
        }
    }

    __syncthreads();

    // ---- epilogue: reduce s_run across ln, fold 2 wc-waves via LDS ----
    float* fred = (float*)lds;             // 256 rows x 2 wc floats
#pragma unroll
    for (int i = 0; i < 4; i++) {
#pragma unroll
        for (int rg = 0; rg < 4; rg++) {
            float es = s_run[i][rg];
#pragma unroll
            for (int off = 8; off; off >>= 1) es += __shfl_xor(es, off);
            if (ln == 0)
                fred[(wr * 64 + i * 16 + lq * 4 + rg) * 2 + wc] = es;
        }
    }
    __syncthreads();
    if (tid < 256) {
        const float tot = fred[tid * 2] + fred[tid * 2 + 1];
        ps[(size_t)(row0 + tid) * PSW + bcg] = tot;
    }
#undef SA
#undef SB
#undef STG8
#undef PH_
}

// ---------------------------------------------------------------------------
// Kernel C (kept): dt via bf16 imgB . fp32 Tsum; ds precomputed.
// ---------------------------------------------------------------------------
__global__ __launch_bounds__(256) void k_finalize(
    const unsigned short* __restrict__ imgB,
    const int* __restrict__ labels, const float* __restrict__ scale_p,
    const float* __restrict__ Tsum, const int* __restrict__ counts,
    const float* __restrict__ ps, const float* __restrict__ dsv,
    float* __restrict__ out)
{
    const float scale = scale_p[0];
    const int tid = threadIdx.x;
    const int lane = tid & 63;
    const int wave = tid >> 6;
    const int rowBase = blockIdx.x * 16 + wave * 4;
    float local = 0.f;
#pragma unroll
    for (int it = 0; it < 4; it++) {
        const int i = rowBase + it;
        const int lab = labels[i];
        const float* sp = Tsum + lab * DD + lane * 8;
        union { uint4 v; unsigned short s[8]; } iv;
        iv.v = *(const uint4*)(imgB + (size_t)i * DD + lane * 8);
        const float4 s0 = *(const float4*)(sp);
        const float4 s1 = *(const float4*)(sp + 4);
        float dt = 0.f;
        dt = fmaf(__uint_as_float((unsigned)iv.s[0] << 16), s0.x, dt);
        dt = fmaf(__uint_as_float((unsigned)iv.s[1] << 16), s0.y, dt);
        dt = fmaf(__uint_as_float((unsigned)iv.s[2] << 16), s0.z, dt);
        dt = fmaf(__uint_as_float((unsigned)iv.s[3] << 16), s0.w, dt);
        dt = fmaf(__uint_as_float((unsigned)iv.s[4] << 16), s1.x, dt);
        dt = fmaf(__uint_as_float((unsigned)iv.s[5] << 16), s1.y, dt);
        dt = fmaf(__uint_as_float((unsigned)iv.s[6] << 16), s1.z, dt);
        dt = fmaf(__uint_as_float((unsigned)iv.s[7] << 16), s1.w, dt);
        float es = (lane < PSW) ? ps[(size_t)i * PSW + lane] : 0.f;
#pragma unroll
        for (int off = 32; off; off >>= 1) {
            dt += __shfl_xor(dt, off);
            es += __shfl_xor(es, off);
        }
        if (lane == 0) {
            const float lse = COFF + __logf(es);
            const int cnt = counts[lab] - 1;
            if (cnt > 0) {
                const float row_sum = scale * (dt - dsv[i]) - (float)cnt * lse;
                local += row_sum / (float)cnt;
            }
        }
    }
    __shared__ float red[4];
    if (lane == 0) red[wave] = local;
    __syncthreads();
    if (tid == 0) {
        const float t = red[0] + red[1] + red[2] + red[3];
        atomicAdd(out, -t / (float)NN);
    }
}

// ---------------------------------------------------------------------------
extern "C" void kernel_launch(void* const* d_in, const int* in_sizes, int n_in,
                              void* d_out, int out_size, void* d_ws, size_t ws_size,
                              hipStream_t stream)
{
    const float* img     = (const float*)d_in[0];
    const float* txt     = (const float*)d_in[1];
    const float* scale_p = (const float*)d_in[2];
    const int*   labels  = (const int*)d_in[3];
    float* out = (float*)d_out;

    char* ws = (char*)d_ws;
    float* ps    = (float*)(ws);                                  // 256 KB (8192 x 8)
    float* Tsum  = (float*)(ws + (1 << 18));                      // 16 KB
    int*   counts = (int*)(ws + (1 << 18) + NSRC * DD * 4);
    float* dsv   = (float*)(ws + 0x48000);                        // 32 KB
    unsigned short* imgB = (unsigned short*)(ws + 2 * 1024 * 1024);   // 8 MB
    unsigned short* txtB = (unsigned short*)(ws + 10 * 1024 * 1024);  // 8 MB

    hipMemsetAsync(ws + (1 << 18), 0, NSRC * DD * 4 + 64, stream);  // Tsum+counts

    k_prep<<<128 + NN / 4, 256, 0, stream>>>(
        img, txt, labels, imgB, txtB, Tsum, counts, dsv, out);
    k_lse_mfma256<<<256, 512, 0, stream>>>(imgB, txtB, scale_p, ps);
    k_finalize<<<NN / 16, 256, 0, stream>>>(imgB, labels, scale_p,
                                            Tsum, counts, ps, dsv, out);
}

// Round 14
// 157.552 us; speedup vs baseline: 1.0597x; 1.0013x over previous
//
#include <hip/hip_runtime.h>
#include <cmath>

#define NN 8192
#define DD 512
#define NSRC 8
#define PSW 8                  // ps partials per row = 8 column groups
#define COFF 100.0f            // fixed softmax offset

typedef __bf16 bf16x8 __attribute__((ext_vector_type(8)));
typedef float  f32x4  __attribute__((ext_vector_type(4)));

__device__ __forceinline__ unsigned short f2bf(float f) {
    unsigned u = __float_as_uint(f);
    u += 0x7fffu + ((u >> 16) & 1u);
    return (unsigned short)(u >> 16);
}

// ---------------------------------------------------------------------------
// Kernel A (kept): blocks 0..127 per-source text sums; blocks 128..: wave-per-
// row cast of img+txt AND per-row img.txt dot (ds). Block 128 zeroes out[0].
// ---------------------------------------------------------------------------
__global__ __launch_bounds__(256) void k_prep(
    const float* __restrict__ img, const float* __restrict__ txt,
    const int* __restrict__ labels,
    unsigned short* __restrict__ imgB, unsigned short* __restrict__ txtB,
    float* __restrict__ Tsum, int* __restrict__ counts,
    float* __restrict__ dsv, float* __restrict__ out)
{
    const int tid = threadIdx.x;
    if (blockIdx.x >= 128) {
        if (blockIdx.x == 128 && tid == 0) out[0] = 0.f;
        const int wv   = tid >> 6;
        const int lane = tid & 63;
        const int row  = (blockIdx.x - 128) * 4 + wv;
        const size_t base = (size_t)row * DD + lane * 8;
        const float4 i0 = *(const float4*)(img + base);
        const float4 i1 = *(const float4*)(img + base + 4);
        const float4 t0 = *(const float4*)(txt + base);
        const float4 t1 = *(const float4*)(txt + base + 4);
        union { unsigned short s[8]; uint4 v; } oi, ot;
        oi.s[0] = f2bf(i0.x); oi.s[1] = f2bf(i0.y); oi.s[2] = f2bf(i0.z); oi.s[3] = f2bf(i0.w);
        oi.s[4] = f2bf(i1.x); oi.s[5] = f2bf(i1.y); oi.s[6] = f2bf(i1.z); oi.s[7] = f2bf(i1.w);
        ot.s[0] = f2bf(t0.x); ot.s[1] = f2bf(t0.y); ot.s[2] = f2bf(t0.z); ot.s[3] = f2bf(t0.w);
        ot.s[4] = f2bf(t1.x); ot.s[5] = f2bf(t1.y); ot.s[6] = f2bf(t1.z); ot.s[7] = f2bf(t1.w);
        *(uint4*)(imgB + base) = oi.v;
        *(uint4*)(txtB + base) = ot.v;
        float ds = i0.x * t0.x + i0.y * t0.y + i0.z * t0.z + i0.w * t0.w
                 + i1.x * t1.x + i1.y * t1.y + i1.z * t1.z + i1.w * t1.w;
#pragma unroll
        for (int off = 32; off; off >>= 1) ds += __shfl_xor(ds, off);
        if (lane == 0) dsv[row] = ds;
        return;
    }
    __shared__ float Tacc[NSRC * DD];
    __shared__ int cacc[NSRC];
    const int d0 = 2 * tid;
#pragma unroll
    for (int s = 0; s < NSRC; s++) {
        Tacc[s * DD + d0] = 0.f;
        Tacc[s * DD + d0 + 1] = 0.f;
    }
    if (tid < NSRC) cacc[tid] = 0;
    __syncthreads();

    const int row0 = blockIdx.x * 64;
    if (tid < 64) atomicAdd(&cacc[labels[row0 + tid]], 1);

    for (int j = 0; j < 64; j++) {
        const int lab = labels[row0 + j];
        const float2 v = *(const float2*)(txt + (size_t)(row0 + j) * DD + d0);
        Tacc[lab * DD + d0]     += v.x;
        Tacc[lab * DD + d0 + 1] += v.y;
    }
    __syncthreads();
#pragma unroll
    for (int k = 0; k < NSRC * DD / 256; k++) {
        const int e = k * 256 + tid;
        atomicAdd(&Tsum[e], Tacc[e]);
    }
    if (tid < NSRC) atomicAdd(&counts[tid], cacc[tid]);
}

// ---------------------------------------------------------------------------
// Kernel B (R14): R13's minimal-sync machine + WAVE-OWNED STAGING:
//  - wc==0 wave (wr) stages A quantum wr (8 stripe-loads); wc==1 wave (wr)
//    stages B quantum wr (8 loads). Dest lane-linear (HW constraint); source
//    chunk per lane = (lane&7)^(lane>>3) -> slot(r,c) holds src chunk
//    c^(r&7), identical to the proven read mapping.
//  - EARLY-AF: after a wave's own vmcnt(0) (its A stores landed), wc==0
//    waves prefetch af(t+1) from the incoming buffer BEFORE the barrier.
//    JH0's serial read burst drops 96 -> 64 block-wide reads; the 32 early
//    reads drain inside the barrier-skew window.
//  - WAR: early reads touch only the reader's own self-staged A region
//    (landed); disjoint from in-flight B stores; region next overwritten
//    >=2 barriers later. wc==1 waves read af at JH0 as before (their af is
//    staged by the sibling wave -> needs the barrier).
// Sync structure (1 barrier + 1 vmcnt(0) per tile) unchanged from R13.
// ---------------------------------------------------------------------------
__global__ __launch_bounds__(512, 2) void k_lse_mfma256(
    const unsigned short* __restrict__ imgB, const unsigned short* __restrict__ txtB,
    const float* __restrict__ scale_p, float* __restrict__ ps)
{
    __shared__ uint4 lds[8192];            // 128 KiB
    const float scale = scale_p[0];
    const int tid  = threadIdx.x;
    const int lane = tid & 63;
    const int w    = tid >> 6;
    const int wr   = w >> 1;               // 0..3: 64-row quarter / B quantum
    const int wc   = w & 1;                // 0..1: 128-col half / stage role
    const int lq   = lane >> 4;
    const int ln   = lane & 15;
    const int c    = blockIdx.x & 7;       // XCD (round-robin dispatch)
    const int l    = blockIdx.x >> 3;
    const int by   = c * 4 + (l >> 3);     // row panel 0..31
    const int bcg  = l & 7;                // column group 0..7
    const int row0    = by * 256;
    const int colBase = bcg * 1024;

    const int xsw = ln & 7;
    const int sl  = (lane & 7) ^ (lane >> 3);   // staged source chunk

    int aA[2][2], aB[2][2];
#pragma unroll
    for (int b = 0; b < 2; b++)
#pragma unroll
        for (int ks = 0; ks < 2; ks++) {
            const int perm = ((ks << 2) + lq) ^ xsw;
            aA[b][ks] = b * 65536 + (wr * 64 + ln) * 128 + perm * 16;
            aB[b][ks] = b * 65536 + 32768 + (wc * 128 + ln) * 128 + perm * 16;
        }
    // per-lane staging source bases (element units)
    const unsigned short* gSA = imgB
        + (size_t)(row0 + wr * 64 + (lane >> 3)) * DD + sl * 8;
    const unsigned short* gSB = txtB
        + (size_t)(colBase + wr * 64 + (lane >> 3)) * DD + sl * 8;

// wave-owned staging of tile T into BUF: wc0 -> A quantum wr, wc1 -> B q wr.
#define STG(BUF, T)                                                            \
    do {                                                                       \
        if (wc == 0) {                                                         \
            _Pragma("unroll") for (int j = 0; j < 8; j++) {                    \
                const unsigned short* g = gSA + j * 4096 + (((T) & 7) << 6);   \
                __builtin_amdgcn_global_load_lds(                              \
                    (const __attribute__((address_space(1))) void*)g,          \
                    (__attribute__((address_space(3))) void*)                  \
                        &lds[(BUF) * 4096 + wr * 512 + j * 64 + lane],         \
                    16, 0, 0);                                                 \
            }                                                                  \
        } else {                                                               \
            _Pragma("unroll") for (int j = 0; j < 8; j++) {                    \
                const unsigned short* g = gSB                                  \
                    + ((size_t)(((T) >> 3) & 3) << 17) + j * 4096              \
                    + (((T) & 7) << 6);                                        \
                __builtin_amdgcn_global_load_lds(                              \
                    (const __attribute__((address_space(1))) void*)g,          \
                    (__attribute__((address_space(3))) void*)                  \
                        &lds[(BUF) * 4096 + 2048 + wr * 512 + j * 64 + lane],  \
                    16, 0, 0);                                                 \
            }                                                                  \
        }                                                                      \
    } while (0)

#define RD_AF(BUF)                                                             \
    _Pragma("unroll") for (int ks = 0; ks < 2; ks++)                           \
        _Pragma("unroll") for (int ii = 0; ii < 4; ii++)                       \
            af[ii][ks] = *reinterpret_cast<const bf16x8*>(                     \
                (const char*)lds + aA[BUF][ks] + ii * 2048);

#define EARLY_AF(BUF) if (wc == 0) { RD_AF(BUF) }

// Phase JH in BUF: [af for wc1 at JH0] + bf reads + STG -> sched_barrier ->
// setprio(1) MFMA setprio(0). No barrier inside (R13 structure).
#define PH_(BUF, JH, RA, STG_)                                                 \
    do {                                                                       \
        if ((RA) && wc == 1) { RD_AF(BUF) }                                    \
        bf16x8 bf[2][2];                                                       \
        _Pragma("unroll") for (int ks = 0; ks < 2; ks++)                       \
            _Pragma("unroll") for (int jj = 0; jj < 2; jj++)                   \
                bf[jj][ks] = *reinterpret_cast<const bf16x8*>(                 \
                    (const char*)lds + aB[BUF][ks] + (JH) * 4096 + jj * 2048); \
        STG_;                                                                  \
        __builtin_amdgcn_sched_barrier(0);                                     \
        __builtin_amdgcn_s_setprio(1);                                         \
        _Pragma("unroll") for (int ks = 0; ks < 2; ks++) {                     \
            _Pragma("unroll") for (int ii = 0; ii < 4; ii++) {                 \
                _Pragma("unroll") for (int jj = 0; jj < 2; jj++) {             \
                    acc[ii][(JH) * 2 + jj] =                                   \
                        __builtin_amdgcn_mfma_f32_16x16x32_bf16(               \
                            af[ii][ks], bf[jj][ks], acc[ii][(JH) * 2 + jj],    \
                            0, 0, 0);                                          \
                }                                                              \
            }                                                                  \
        }                                                                      \
        __builtin_amdgcn_s_setprio(0);                                         \
    } while (0)

    f32x4 acc[4][8];
    f32x4 s_run[4];
#pragma unroll
    for (int i = 0; i < 4; i++) {
        s_run[i] = (f32x4){0.f, 0.f, 0.f, 0.f};
#pragma unroll
        for (int j = 0; j < 8; j++) acc[i][j] = (f32x4){0.f, 0.f, 0.f, 0.f};
    }
    bf16x8 af[4][2];

    // ---- prologue: stage tile 0, drain own loads, early-af, sync ----
    STG(0, 0);
    asm volatile("s_waitcnt vmcnt(0)" ::: "memory");
    EARLY_AF(0);
    __builtin_amdgcn_s_barrier();

#pragma unroll 1
    for (int v0 = 0; v0 < 32; v0 += 2) {
        // ---- tile v0 (buf0): stage v0+1 -> buf1 at JH0 ----
        PH_(0, 0, 1, STG(1, v0 + 1));
        PH_(0, 1, 0, (void)0);
        PH_(0, 2, 0, (void)0);
        PH_(0, 3, 0, (void)0);
        asm volatile("s_waitcnt vmcnt(0)" ::: "memory");
        EARLY_AF(1);                       // own A stores landed; pre-barrier
        __builtin_amdgcn_s_barrier();      // bar_S: v0+1 staged, buf0 retired
        // ---- tile v0+1 (buf1): stage v0+2 -> buf0 at JH0 ----
        PH_(1, 0, 1, STG(0, v0 + 2));
        PH_(1, 1, 0, (void)0);
        PH_(1, 2, 0, (void)0);
        PH_(1, 3, 0, (void)0);
        asm volatile("s_waitcnt vmcnt(0)" ::: "memory");
        EARLY_AF(0);
        __builtin_amdgcn_s_barrier();      // bar_S'
        if ((v0 & 6) == 6) {
            // ct boundary: register-only exp flush (no barrier, no loads)
#pragma unroll
            for (int i = 0; i < 4; i++) {
#pragma unroll
                for (int rg = 0; rg < 4; rg++) {
                    float es = s_run[i][rg];
#pragma unroll
                    for (int j = 0; j < 8; j++)
                        es += __expf(fmaf(acc[i][j][rg], scale, -COFF));
                    s_run[i][rg] = es;
                }
#pragma unroll
                for (int j = 0; j < 8; j++)
                    acc[i][j] = (f32x4){0.f, 0.f, 0.f, 0.f};
            }
        }
    }

    __syncthreads();

    // ---- epilogue: reduce s_run across ln, fold 2 wc-waves via LDS ----
    float* fred = (float*)lds;             // 256 rows x 2 wc floats
#pragma unroll
    for (int i = 0; i < 4; i++) {
#pragma unroll
        for (int rg = 0; rg < 4; rg++) {
            float es = s_run[i][rg];
#pragma unroll
            for (int off = 8; off; off >>= 1) es += __shfl_xor(es, off);
            if (ln == 0)
                fred[(wr * 64 + i * 16 + lq * 4 + rg) * 2 + wc] = es;
        }
    }
    __syncthreads();
    if (tid < 256) {
        const float tot = fred[tid * 2] + fred[tid * 2 + 1];
        ps[(size_t)(row0 + tid) * PSW + bcg] = tot;
    }
#undef STG
#undef RD_AF
#undef EARLY_AF
#undef PH_
}

// ---------------------------------------------------------------------------
// Kernel C (kept): dt via bf16 imgB . fp32 Tsum; ds precomputed.
// ---------------------------------------------------------------------------
__global__ __launch_bounds__(256) void k_finalize(
    const unsigned short* __restrict__ imgB,
    const int* __restrict__ labels, const float* __restrict__ scale_p,
    const float* __restrict__ Tsum, const int* __restrict__ counts,
    const float* __restrict__ ps, const float* __restrict__ dsv,
    float* __restrict__ out)
{
    const float scale = scale_p[0];
    const int tid = threadIdx.x;
    const int lane = tid & 63;
    const int wave = tid >> 6;
    const int rowBase = blockIdx.x * 16 + wave * 4;
    float local = 0.f;
#pragma unroll
    for (int it = 0; it < 4; it++) {
        const int i = rowBase + it;
        const int lab = labels[i];
        const float* sp = Tsum + lab * DD + lane * 8;
        union { uint4 v; unsigned short s[8]; } iv;
        iv.v = *(const uint4*)(imgB + (size_t)i * DD + lane * 8);
        const float4 s0 = *(const float4*)(sp);
        const float4 s1 = *(const float4*)(sp + 4);
        float dt = 0.f;
        dt = fmaf(__uint_as_float((unsigned)iv.s[0] << 16), s0.x, dt);
        dt = fmaf(__uint_as_float((unsigned)iv.s[1] << 16), s0.y, dt);
        dt = fmaf(__uint_as_float((unsigned)iv.s[2] << 16), s0.z, dt);
        dt = fmaf(__uint_as_float((unsigned)iv.s[3] << 16), s0.w, dt);
        dt = fmaf(__uint_as_float((unsigned)iv.s[4] << 16), s1.x, dt);
        dt = fmaf(__uint_as_float((unsigned)iv.s[5] << 16), s1.y, dt);
        dt = fmaf(__uint_as_float((unsigned)iv.s[6] << 16), s1.z, dt);
        dt = fmaf(__uint_as_float((unsigned)iv.s[7] << 16), s1.w, dt);
        float es = (lane < PSW) ? ps[(size_t)i * PSW + lane] : 0.f;
#pragma unroll
        for (int off = 32; off; off >>= 1) {
            dt += __shfl_xor(dt, off);
            es += __shfl_xor(es, off);
        }
        if (lane == 0) {
            const float lse = COFF + __logf(es);
            const int cnt = counts[lab] - 1;
            if (cnt > 0) {
                const float row_sum = scale * (dt - dsv[i]) - (float)cnt * lse;
                local += row_sum / (float)cnt;
            }
        }
    }
    __shared__ float red[4];
    if (lane == 0) red[wave] = local;
    __syncthreads();
    if (tid == 0) {
        const float t = red[0] + red[1] + red[2] + red[3];
        atomicAdd(out, -t / (float)NN);
    }
}

// ---------------------------------------------------------------------------
extern "C" void kernel_launch(void* const* d_in, const int* in_sizes, int n_in,
                              void* d_out, int out_size, void* d_ws, size_t ws_size,
                              hipStream_t stream)
{
    const float* img     = (const float*)d_in[0];
    const float* txt     = (const float*)d_in[1];
    const float* scale_p = (const float*)d_in[2];
    const int*   labels  = (const int*)d_in[3];
    float* out = (float*)d_out;

    char* ws = (char*)d_ws;
    float* ps    = (float*)(ws);                                  // 256 KB (8192 x 8)
    float* Tsum  = (float*)(ws + (1 << 18));                      // 16 KB
    int*   counts = (int*)(ws + (1 << 18) + NSRC * DD * 4);
    float* dsv   = (float*)(ws + 0x48000);                        // 32 KB
    unsigned short* imgB = (unsigned short*)(ws + 2 * 1024 * 1024);   // 8 MB
    unsigned short* txtB = (unsigned short*)(ws + 10 * 1024 * 1024);  // 8 MB

    hipMemsetAsync(ws + (1 << 18), 0, NSRC * DD * 4 + 64, stream);  // Tsum+counts

    k_prep<<<128 + NN / 4, 256, 0, stream>>>(
        img, txt, labels, imgB, txtB, Tsum, counts, dsv, out);
    k_lse_mfma256<<<256, 512, 0, stream>>>(imgB, txtB, scale_p, ps);
    k_finalize<<<NN / 16, 256, 0, stream>>>(imgB, labels, scale_p,
                                            Tsum, counts, ps, dsv, out);
}

// Round 15
// 153.929 us; speedup vs baseline: 1.0846x; 1.0235x over previous
//
#include <hip/hip_runtime.h>
#include <cmath>

#define NN 8192
#define DD 512
#define NSRC 8
#define PSW 8                  // ps partials per row = 8 column groups
#define COFF 100.0f            // fixed softmax offset

typedef __bf16 bf16x8 __attribute__((ext_vector_type(8)));
typedef float  f32x4  __attribute__((ext_vector_type(4)));

__device__ __forceinline__ unsigned short f2bf(float f) {
    unsigned u = __float_as_uint(f);
    u += 0x7fffu + ((u >> 16) & 1u);
    return (unsigned short)(u >> 16);
}

// ---------------------------------------------------------------------------
// Kernel A (R13 final): blocks 0..127 per-source text sums; blocks 128..:
// wave-per-row cast of img+txt AND per-row img.txt dot (ds). Block 128
// zeroes out[0] (stream-ordered before k_finalize's atomics).
// ---------------------------------------------------------------------------
__global__ __launch_bounds__(256) void k_prep(
    const float* __restrict__ img, const float* __restrict__ txt,
    const int* __restrict__ labels,
    unsigned short* __restrict__ imgB, unsigned short* __restrict__ txtB,
    float* __restrict__ Tsum, int* __restrict__ counts,
    float* __restrict__ dsv, float* __restrict__ out)
{
    const int tid = threadIdx.x;
    if (blockIdx.x >= 128) {
        if (blockIdx.x == 128 && tid == 0) out[0] = 0.f;
        const int wv   = tid >> 6;
        const int lane = tid & 63;
        const int row  = (blockIdx.x - 128) * 4 + wv;
        const size_t base = (size_t)row * DD + lane * 8;
        const float4 i0 = *(const float4*)(img + base);
        const float4 i1 = *(const float4*)(img + base + 4);
        const float4 t0 = *(const float4*)(txt + base);
        const float4 t1 = *(const float4*)(txt + base + 4);
        union { unsigned short s[8]; uint4 v; } oi, ot;
        oi.s[0] = f2bf(i0.x); oi.s[1] = f2bf(i0.y); oi.s[2] = f2bf(i0.z); oi.s[3] = f2bf(i0.w);
        oi.s[4] = f2bf(i1.x); oi.s[5] = f2bf(i1.y); oi.s[6] = f2bf(i1.z); oi.s[7] = f2bf(i1.w);
        ot.s[0] = f2bf(t0.x); ot.s[1] = f2bf(t0.y); ot.s[2] = f2bf(t0.z); ot.s[3] = f2bf(t0.w);
        ot.s[4] = f2bf(t1.x); ot.s[5] = f2bf(t1.y); ot.s[6] = f2bf(t1.z); ot.s[7] = f2bf(t1.w);
        *(uint4*)(imgB + base) = oi.v;
        *(uint4*)(txtB + base) = ot.v;
        float ds = i0.x * t0.x + i0.y * t0.y + i0.z * t0.z + i0.w * t0.w
                 + i1.x * t1.x + i1.y * t1.y + i1.z * t1.z + i1.w * t1.w;
#pragma unroll
        for (int off = 32; off; off >>= 1) ds += __shfl_xor(ds, off);
        if (lane == 0) dsv[row] = ds;
        return;
    }
    __shared__ float Tacc[NSRC * DD];
    __shared__ int cacc[NSRC];
    const int d0 = 2 * tid;
#pragma unroll
    for (int s = 0; s < NSRC; s++) {
        Tacc[s * DD + d0] = 0.f;
        Tacc[s * DD + d0 + 1] = 0.f;
    }
    if (tid < NSRC) cacc[tid] = 0;
    __syncthreads();

    const int row0 = blockIdx.x * 64;
    if (tid < 64) atomicAdd(&cacc[labels[row0 + tid]], 1);

    for (int j = 0; j < 64; j++) {
        const int lab = labels[row0 + j];
        const float2 v = *(const float2*)(txt + (size_t)(row0 + j) * DD + d0);
        Tacc[lab * DD + d0]     += v.x;
        Tacc[lab * DD + d0 + 1] += v.y;
    }
    __syncthreads();
#pragma unroll
    for (int k = 0; k < NSRC * DD / 256; k++) {
        const int e = k * 256 + tid;
        atomicAdd(&Tsum[e], Tacc[e]);
    }
    if (tid < NSRC) atomicAdd(&counts[tid], cacc[tid]);
}

// ---------------------------------------------------------------------------
// Kernel B (R13 final — session-best GEMM, 67.4 us, MfmaUtil 42%, 1020 TF):
// persistent 256-block, 256x256 tile, 4wr x 2wc single-read fragments
// (192 KB LDS/tile, the wave-grid family minimum), minimal sync:
// ONE barrier + ONE vmcnt(0) per K-tile. Tile T (buf B) stages ALL 8 quanta
// of tile T+1 into buf B^1 at JH0 -> no same-buffer overwrite anywhere
// (buf^1's last readers retired at the previous bar_S). vmcnt(0) at tile end
// drains the 8 loads issued ~2000 cyc earlier. 0-conflict 16-row/ln/lq/xsw
// read pattern; exp flush at ct boundaries is register-only.
// Floor arithmetic: MFMA 2050 + LDS 2260 (85 B/cyc measured) + ~700 skew
// per tile, serial — barrier-compatible overlap attempts (R5/R7/R8/R12/R14)
// all null-to-negative; this is the structure's measured floor.
// ---------------------------------------------------------------------------
__global__ __launch_bounds__(512, 2) void k_lse_mfma256(
    const unsigned short* __restrict__ imgB, const unsigned short* __restrict__ txtB,
    const float* __restrict__ scale_p, float* __restrict__ ps)
{
    __shared__ uint4 lds[8192];            // 128 KiB
    const float scale = scale_p[0];
    const int tid  = threadIdx.x;
    const int lane = tid & 63;
    const int w    = tid >> 6;
    const int wr   = w >> 1;               // 0..3: 64-row quarter
    const int wc   = w & 1;                // 0..1: 128-col half
    const int lq   = lane >> 4;
    const int ln   = lane & 15;
    const int c    = blockIdx.x & 7;       // XCD (round-robin dispatch)
    const int l    = blockIdx.x >> 3;
    const int by   = c * 4 + (l >> 3);     // row panel 0..31
    const int bcg  = l & 7;                // column group 0..7
    const int row0    = by * 256;
    const int colBase = bcg * 1024;

    const int st_r  = tid >> 3;
    const int st_kc = (tid & 7) ^ (st_r & 7);
    const int xsw   = ln & 7;

    int aA[2][2], aB[2][2];
#pragma unroll
    for (int b = 0; b < 2; b++)
#pragma unroll
        for (int ks = 0; ks < 2; ks++) {
            const int perm = ((ks << 2) + lq) ^ xsw;
            aA[b][ks] = b * 65536 + (wr * 64 + ln) * 128 + perm * 16;
            aB[b][ks] = b * 65536 + 32768 + (wc * 128 + ln) * 128 + perm * 16;
        }
    const unsigned short* gA0 = imgB + (size_t)(row0 + st_r) * DD + (st_kc << 3);
    const unsigned short* gB0 = txtB + (size_t)(colBase + st_r) * DD + (st_kc << 3);

#define SA(BUF, Q, T)                                                          \
    { const unsigned short* g = gA0 + ((Q) << 15) + (((T) & 7) << 6);          \
      __builtin_amdgcn_global_load_lds(                                        \
          (const __attribute__((address_space(1))) void*)g,                    \
          (__attribute__((address_space(3))) void*)                            \
              &lds[(BUF) * 4096 + (Q) * 512 + tid], 16, 0, 0); }
#define SB(BUF, Q, T)                                                          \
    { const unsigned short* g = gB0 + ((size_t)(((T) >> 3) & 3) << 17)         \
          + ((Q) << 15) + (((T) & 7) << 6);                                    \
      __builtin_amdgcn_global_load_lds(                                        \
          (const __attribute__((address_space(1))) void*)g,                    \
          (__attribute__((address_space(3))) void*)                            \
              &lds[(BUF) * 4096 + 2048 + (Q) * 512 + tid], 16, 0, 0); }

#define STG8(BUF, T)                                                           \
    SA(BUF, 0, T); SA(BUF, 1, T); SA(BUF, 2, T); SA(BUF, 3, T);                \
    SB(BUF, 0, T); SB(BUF, 1, T); SB(BUF, 2, T); SB(BUF, 3, T)

#define PH_(BUF, JH, RA, STG)                                                  \
    do {                                                                       \
        if (RA) {                                                              \
            _Pragma("unroll") for (int ks = 0; ks < 2; ks++)                   \
                _Pragma("unroll") for (int ii = 0; ii < 4; ii++)               \
                    af[ii][ks] = *reinterpret_cast<const bf16x8*>(             \
                        (const char*)lds + aA[BUF][ks] + ii * 2048);           \
        }                                                                      \
        bf16x8 bf[2][2];                                                       \
        _Pragma("unroll") for (int ks = 0; ks < 2; ks++)                       \
            _Pragma("unroll") for (int jj = 0; jj < 2; jj++)                   \
                bf[jj][ks] = *reinterpret_cast<const bf16x8*>(                 \
                    (const char*)lds + aB[BUF][ks] + (JH) * 4096 + jj * 2048); \
        STG;                                                                   \
        __builtin_amdgcn_sched_barrier(0);                                     \
        __builtin_amdgcn_s_setprio(1);                                         \
        _Pragma("unroll") for (int ks = 0; ks < 2; ks++) {                     \
            _Pragma("unroll") for (int ii = 0; ii < 4; ii++) {                 \
                _Pragma("unroll") for (int jj = 0; jj < 2; jj++) {             \
                    acc[ii][(JH) * 2 + jj] =                                   \
                        __builtin_amdgcn_mfma_f32_16x16x32_bf16(               \
                            af[ii][ks], bf[jj][ks], acc[ii][(JH) * 2 + jj],    \
                            0, 0, 0);                                          \
                }                                                              \
            }                                                                  \
        }                                                                      \
        __builtin_amdgcn_s_setprio(0);                                         \
    } while (0)

    // ---- prologue: stage tile 0 into buf0, drain, sync ----
    STG8(0, 0);
    asm volatile("s_waitcnt vmcnt(0)" ::: "memory");
    __builtin_amdgcn_s_barrier();

    f32x4 acc[4][8];
    f32x4 s_run[4];
#pragma unroll
    for (int i = 0; i < 4; i++) {
        s_run[i] = (f32x4){0.f, 0.f, 0.f, 0.f};
#pragma unroll
        for (int j = 0; j < 8; j++) acc[i][j] = (f32x4){0.f, 0.f, 0.f, 0.f};
    }
    bf16x8 af[4][2];

#pragma unroll 1
    for (int v0 = 0; v0 < 32; v0 += 2) {
        // ---- tile v0 (buf0): stage v0+1 -> buf1 at JH0 ----
        PH_(0, 0, 1, STG8(1, v0 + 1));
        PH_(0, 1, 0, (void)0);
        PH_(0, 2, 0, (void)0);
        PH_(0, 3, 0, (void)0);
        asm volatile("s_waitcnt vmcnt(0)" ::: "memory");
        __builtin_amdgcn_s_barrier();      // bar_S: v0+1 staged, buf0 retired
        // ---- tile v0+1 (buf1): stage v0+2 -> buf0 at JH0 ----
        PH_(1, 0, 1, STG8(0, v0 + 2));
        PH_(1, 1, 0, (void)0);
        PH_(1, 2, 0, (void)0);
        PH_(1, 3, 0, (void)0);
        asm volatile("s_waitcnt vmcnt(0)" ::: "memory");
        __builtin_amdgcn_s_barrier();      // bar_S'
        if ((v0 & 6) == 6) {
            // ct boundary: register-only exp flush (no barrier, no loads)
#pragma unroll
            for (int i = 0; i < 4; i++) {
#pragma unroll
                for (int rg = 0; rg < 4; rg++) {
                    float es = s_run[i][rg];
#pragma unroll
                    for (int j = 0; j < 8; j++)
                        es += __expf(fmaf(acc[i][j][rg], scale, -COFF));
                    s_run[i][rg] = es;
                }
#pragma unroll
                for (int j = 0; j < 8; j++)
                    acc[i][j] = (f32x4){0.f, 0.f, 0.f, 0.f};
            }
        }
    }

    __syncthreads();

    // ---- epilogue: reduce s_run across ln, fold 2 wc-waves via LDS ----
    float* fred = (float*)lds;             // 256 rows x 2 wc floats
#pragma unroll
    for (int i = 0; i < 4; i++) {
#pragma unroll
        for (int rg = 0; rg < 4; rg++) {
            float es = s_run[i][rg];
#pragma unroll
            for (int off = 8; off; off >>= 1) es += __shfl_xor(es, off);
            if (ln == 0)
                fred[(wr * 64 + i * 16 + lq * 4 + rg) * 2 + wc] = es;
        }
    }
    __syncthreads();
    if (tid < 256) {
        const float tot = fred[tid * 2] + fred[tid * 2 + 1];
        ps[(size_t)(row0 + tid) * PSW + bcg] = tot;
    }
#undef SA
#undef SB
#undef STG8
#undef PH_
}

// ---------------------------------------------------------------------------
// Kernel C (R13 final): dt via bf16 imgB . fp32 Tsum; ds precomputed.
// ---------------------------------------------------------------------------
__global__ __launch_bounds__(256) void k_finalize(
    const unsigned short* __restrict__ imgB,
    const int* __restrict__ labels, const float* __restrict__ scale_p,
    const float* __restrict__ Tsum, const int* __restrict__ counts,
    const float* __restrict__ ps, const float* __restrict__ dsv,
    float* __restrict__ out)
{
    const float scale = scale_p[0];
    const int tid = threadIdx.x;
    const int lane = tid & 63;
    const int wave = tid >> 6;
    const int rowBase = blockIdx.x * 16 + wave * 4;
    float local = 0.f;
#pragma unroll
    for (int it = 0; it < 4; it++) {
        const int i = rowBase + it;
        const int lab = labels[i];
        const float* sp = Tsum + lab * DD + lane * 8;
        union { uint4 v; unsigned short s[8]; } iv;
        iv.v = *(const uint4*)(imgB + (size_t)i * DD + lane * 8);
        const float4 s0 = *(const float4*)(sp);
        const float4 s1 = *(const float4*)(sp + 4);
        float dt = 0.f;
        dt = fmaf(__uint_as_float((unsigned)iv.s[0] << 16), s0.x, dt);
        dt = fmaf(__uint_as_float((unsigned)iv.s[1] << 16), s0.y, dt);
        dt = fmaf(__uint_as_float((unsigned)iv.s[2] << 16), s0.z, dt);
        dt = fmaf(__uint_as_float((unsigned)iv.s[3] << 16), s0.w, dt);
        dt = fmaf(__uint_as_float((unsigned)iv.s[4] << 16), s1.x, dt);
        dt = fmaf(__uint_as_float((unsigned)iv.s[5] << 16), s1.y, dt);
        dt = fmaf(__uint_as_float((unsigned)iv.s[6] << 16), s1.z, dt);
        dt = fmaf(__uint_as_float((unsigned)iv.s[7] << 16), s1.w, dt);
        float es = (lane < PSW) ? ps[(size_t)i * PSW + lane] : 0.f;
#pragma unroll
        for (int off = 32; off; off >>= 1) {
            dt += __shfl_xor(dt, off);
            es += __shfl_xor(es, off);
        }
        if (lane == 0) {
            const float lse = COFF + __logf(es);
            const int cnt = counts[lab] - 1;
            if (cnt > 0) {
                const float row_sum = scale * (dt - dsv[i]) - (float)cnt * lse;
                local += row_sum / (float)cnt;
            }
        }
    }
    __shared__ float red[4];
    if (lane == 0) red[wave] = local;
    __syncthreads();
    if (tid == 0) {
        const float t = red[0] + red[1] + red[2] + red[3];
        atomicAdd(out, -t / (float)NN);
    }
}

// ---------------------------------------------------------------------------
extern "C" void kernel_launch(void* const* d_in, const int* in_sizes, int n_in,
                              void* d_out, int out_size, void* d_ws, size_t ws_size,
                              hipStream_t stream)
{
    const float* img     = (const float*)d_in[0];
    const float* txt     = (const float*)d_in[1];
    const float* scale_p = (const float*)d_in[2];
    const int*   labels  = (const int*)d_in[3];
    float* out = (float*)d_out;

    char* ws = (char*)d_ws;
    float* ps    = (float*)(ws);                                  // 256 KB (8192 x 8)
    float* Tsum  = (float*)(ws + (1 << 18));                      // 16 KB
    int*   counts = (int*)(ws + (1 << 18) + NSRC * DD * 4);
    float* dsv   = (float*)(ws + 0x48000);                        // 32 KB
    unsigned short* imgB = (unsigned short*)(ws + 2 * 1024 * 1024);   // 8 MB
    unsigned short* txtB = (unsigned short*)(ws + 10 * 1024 * 1024);  // 8 MB

    hipMemsetAsync(ws + (1 << 18), 0, NSRC * DD * 4 + 64, stream);  // Tsum+counts

    k_prep<<<128 + NN / 4, 256, 0, stream>>>(
        img, txt, labels, imgB, txtB, Tsum, counts, dsv, out);
    k_lse_mfma256<<<256, 512, 0, stream>>>(imgB, txtB, scale_p, ps);
    k_finalize<<<NN / 16, 256, 0, stream>>>(imgB, labels, scale_p,
                                            Tsum, counts, ps, dsv, out);
}